// Round 5
// baseline (233.129 us; speedup 1.0000x reference)
//
#include <hip/hip_runtime.h>
#include <hip/hip_bf16.h>
#include <math.h>

// ---------------------------------------------------------------------------
// SAContrastiveAdversarialLoss on MI355X (gfx950)
// B=8192, D=128, S=64. Output: scalar fp32.
//
// R5: m93-style LDS-staged main kernel with SMALL per-wave register state
// (R3 showed big pinned state across barriers => spills; R4 showed the
// no-LDS structure caps at 4 waves/SIMD and ~500cyc B-load latency).
//   block = 4 waves; wave w owns 16 rows (afrag[4] = 16 VGPRs only).
//   B stage = 64 cols x 256 B = 16 KB LDS, double-buffered (32 KB).
//   block spans 1024 cols = 16 stages; 1 barrier/stage.
//   chunk swizzle p=(j+3*col)&15 puts ds_read/write_b128 at the 8-pass
//   bank floor (no above-floor conflicts).
//   Staging = plain register round-trip (b128 global loads, coalesced
//   4 KB/wave-instr), prefetched one stage ahead.
// ---------------------------------------------------------------------------

#define NROWS 8192
#define DFEAT 128

typedef __bf16 bf16_t;
typedef __bf16 bf16x8 __attribute__((ext_vector_type(8)));
typedef __bf16 bf16x2 __attribute__((ext_vector_type(2)));
typedef float  f32x4  __attribute__((ext_vector_type(4)));

__device__ __forceinline__ float fexp2(float x) {
#if __has_builtin(__builtin_amdgcn_exp2f)
  return __builtin_amdgcn_exp2f(x);
#else
  return exp2f(x);
#endif
}

// ---------------------------------------------------------------------------
// prep: one wave per row. Computes row norms + diagonal dots, writes
//   Abuf[row] = bf16( n1 * 10*log2(e) )   (A operand, scale folded in)
//   Kc[row]         = bf16( n2 )          (keys for e12)
//   Kc[8192+row]    = bf16( n1 )          (keys for e11)
//   numv[row] = exp(10*cos(z1,z2)),  d11v[row] = exp(10*cos(z1,z1))
// Also zeroes T[row] and (block 0) the output scalar.
__global__ void sa_prep_kernel(const float* __restrict__ z1,
                               const float* __restrict__ z2,
                               bf16_t* __restrict__ Abuf,
                               bf16_t* __restrict__ Kc,
                               float* __restrict__ numv,
                               float* __restrict__ d11v,
                               float* __restrict__ T,
                               float* __restrict__ out) {
  int wave = threadIdx.x >> 6;
  int lane = threadIdx.x & 63;
  int row  = blockIdx.x * 4 + wave;

  const float2* z1p = (const float2*)(z1 + row * DFEAT);
  const float2* z2p = (const float2*)(z2 + row * DFEAT);
  float2 a = z1p[lane];
  float2 b = z2p[lane];

  float s1  = a.x * a.x + a.y * a.y;
  float s2  = b.x * b.x + b.y * b.y;
  float s12 = a.x * b.x + a.y * b.y;
#pragma unroll
  for (int m = 32; m; m >>= 1) {
    s1  += __shfl_xor(s1, m, 64);
    s2  += __shfl_xor(s2, m, 64);
    s12 += __shfl_xor(s12, m, 64);
  }
  float r1 = 1.0f / fmaxf(sqrtf(s1), 1e-8f);  // COS_EPS
  float r2 = 1.0f / fmaxf(sqrtf(s2), 1e-8f);

  const float SCL = 14.426950408889634f;  // 10 * log2(e), folds /tau + exp2

  bf16x2 av;  av[0] = (bf16_t)(a.x * r1 * SCL); av[1] = (bf16_t)(a.y * r1 * SCL);
  bf16x2 k2v; k2v[0] = (bf16_t)(b.x * r2);      k2v[1] = (bf16_t)(b.y * r2);
  bf16x2 k1v; k1v[0] = (bf16_t)(a.x * r1);      k1v[1] = (bf16_t)(a.y * r1);

  ((bf16x2*)(Abuf + row * DFEAT))[lane]            = av;
  ((bf16x2*)(Kc + row * DFEAT))[lane]              = k2v;
  ((bf16x2*)(Kc + (NROWS + row) * DFEAT))[lane]    = k1v;

  if (lane == 0) {
    numv[row] = expf(10.0f * s12 * r1 * r2);
    d11v[row] = expf(10.0f * s1 * r1 * r1);
    T[row]    = 0.0f;
  }
  if (blockIdx.x == 0 && threadIdx.x == 0) out[0] = 0.0f;
}

// ---------------------------------------------------------------------------
// main: fused "row-sum of exp(sim)" over the virtual 8192x16384 matrix.
// Grid (128, 16): rowBase = bx*64 (wave w -> rows +w*16), colBase = by*1024.
// Per stage (64 cols): each thread stages 64 B (4x b128 global -> LDS with
// swizzle), 1 barrier, then each wave does 4 col-tiles x (4 ds_read_b128 +
// 4 chained MFMA + 4 exp2-acc). Next stage's global loads are issued before
// the barrier so their latency overlaps compute + other blocks.
// MFMA C/D layout: col=lane&15, row=(lane>>4)*4+reg.
__global__ __launch_bounds__(256)
void sa_main_kernel(const bf16_t* __restrict__ Abuf,
                    const bf16_t* __restrict__ Kc,
                    float* __restrict__ T) {
  __shared__ __align__(16) char smem[2][16384];

  int tid  = threadIdx.x;
  int wave = tid >> 6;
  int lane = tid & 63;
  int quad = lane >> 4;
  int l15  = lane & 15;

  int rowBase = blockIdx.x * 64;
  int colBase = blockIdx.y * 1024;

  // A fragments: 16 rows per wave -> only 16 VGPRs pinned across barriers.
  bf16x8 afrag[4];
  {
    const bf16_t* ap = Abuf + (rowBase + wave * 16 + l15) * DFEAT + quad * 8;
#pragma unroll
    for (int kf = 0; kf < 4; ++kf)
      afrag[kf] = *(const bf16x8*)(ap + kf * 32);
  }

  f32x4 sums = {0.f, 0.f, 0.f, 0.f};

  const char* gbase = (const char*)Kc + (size_t)colBase * 256;  // 256 B/col

  // prefetch stage 0 into registers (4x int4 = 16 VGPRs)
  int4 st[4];
#pragma unroll
  for (int i = 0; i < 4; ++i)
    st[i] = *(const int4*)(gbase + (tid * 4 + i) * 16);

  for (int s = 0; s < 16; ++s) {
    // write staged regs -> LDS buffer s&1 with chunk swizzle
    char* lbuf = smem[s & 1];
#pragma unroll
    for (int i = 0; i < 4; ++i) {
      int g   = tid * 4 + i;       // 16B-chunk index in stage (0..1023)
      int col = g >> 4;            // 0..63
      int j   = g & 15;            // chunk within col
      *(int4*)(lbuf + col * 256 + ((j + 3 * col) & 15) * 16) = st[i];
    }
    // prefetch next stage (latency overlapped by compute below)
    if (s + 1 < 16) {
      const char* gs = gbase + (size_t)(s + 1) * 16384;
#pragma unroll
      for (int i = 0; i < 4; ++i)
        st[i] = *(const int4*)(gs + (tid * 4 + i) * 16);
    }
    __syncthreads();

    const char* rb = smem[s & 1];
#pragma unroll
    for (int ct = 0; ct < 4; ++ct) {
      int col = ct * 16 + l15;
      bf16x8 bfrag[4];
#pragma unroll
      for (int kf = 0; kf < 4; ++kf) {
        int p = (quad + 4 * kf + 3 * col) & 15;  // un-swizzle
        bfrag[kf] = *(const bf16x8*)(rb + col * 256 + p * 16);
      }
      f32x4 c = {0.f, 0.f, 0.f, 0.f};
#pragma unroll
      for (int kf = 0; kf < 4; ++kf)
        c = __builtin_amdgcn_mfma_f32_16x16x32_bf16(afrag[kf], bfrag[kf], c,
                                                    0, 0, 0);
#pragma unroll
      for (int r = 0; r < 4; ++r) sums[r] += fexp2(c[r]);
    }
    // no second barrier needed: next iteration writes the OTHER buffer, and
    // __syncthreads drains lgkmcnt so no wave passes it with reads pending.
  }

  // Reduce across the 16 cols held per quad-group; lane l15==0 of each quad
  // commits 4 row partial-sums.
#pragma unroll
  for (int r = 0; r < 4; ++r) {
    float v = sums[r];
    v += __shfl_xor(v, 1, 64);
    v += __shfl_xor(v, 2, 64);
    v += __shfl_xor(v, 4, 64);
    v += __shfl_xor(v, 8, 64);
    if (l15 == 0)
      atomicAdd(&T[rowBase + wave * 16 + quad * 4 + r], v);
  }
}

// ---------------------------------------------------------------------------
// tail: adversarial term (one wave per row, S=64 == wave width) fused with
// the per-row contrastive finalize (lane 0 of each wave).
__global__ void sa_tail_kernel(const float* __restrict__ T,
                               const float* __restrict__ numv,
                               const float* __restrict__ d11v,
                               const float* __restrict__ c,
                               const float* __restrict__ lab,
                               float* __restrict__ out) {
  int wave = threadIdx.x >> 6;
  int lane = threadIdx.x & 63;
  int row  = blockIdx.x * 4 + wave;

  float cv = c[row * 64 + lane];
  float lv = lab[row * 64 + lane];

  float ss = cv * cv;
  float bestv = lv;
  int   besti = lane;
#pragma unroll
  for (int m = 32; m; m >>= 1) {
    ss += __shfl_xor(ss, m, 64);
    float ov = __shfl_xor(bestv, m, 64);
    int   oi = __shfl_xor(besti, m, 64);
    if (ov > bestv || (ov == bestv && oi < besti)) { bestv = ov; besti = oi; }
  }
  float picked = __shfl(cv, besti, 64) / fmaxf(sqrtf(ss), 1e-12f);
  float term = -logf(1e-12f + 1.0f - picked);  // LAM = 1

  __shared__ float acc[4];
  if (lane == 0) {
    float denom = T[row] - d11v[row];
    float v = -logf(1e-12f + numv[row] / denom);
    term += v * (1.0f / 134209536.0f);  // 1 / (B*(2B-1)) = 1/(8192*16383)
    acc[wave] = term;
  }
  __syncthreads();
  if (threadIdx.x == 0)
    atomicAdd(out, acc[0] + acc[1] + acc[2] + acc[3]);
}

// ---------------------------------------------------------------------------
extern "C" void kernel_launch(void* const* d_in, const int* in_sizes, int n_in,
                              void* d_out, int out_size, void* d_ws,
                              size_t ws_size, hipStream_t stream) {
  const float* z1  = (const float*)d_in[0];  // [8192,128]
  const float* z2  = (const float*)d_in[1];  // [8192,128]
  const float* co  = (const float*)d_in[2];  // [8192,64]
  const float* lab = (const float*)d_in[3];  // [8192,64]
  float* out = (float*)d_out;

  char* ws = (char*)d_ws;
  bf16_t* Abuf = (bf16_t*)ws;                         // 8192*128*2  = 2 MB
  bf16_t* Kc   = (bf16_t*)(ws + 2u * 1024 * 1024);    // 16384*128*2 = 4 MB
  float*  T    = (float*)(ws + 7u * 1024 * 1024);     // 32 KB
  float*  numv = T + NROWS;
  float*  d11v = numv + NROWS;

  sa_prep_kernel<<<NROWS / 4, 256, 0, stream>>>(z1, z2, Abuf, Kc, numv, d11v,
                                                T, out);
  sa_main_kernel<<<dim3(NROWS / 64, 16), 256, 0, stream>>>(Abuf, Kc, T);
  sa_tail_kernel<<<NROWS / 4, 256, 0, stream>>>(T, numv, d11v, co, lab, out);
}

// Round 6
// 204.871 us; speedup vs baseline: 1.1379x; 1.1379x over previous
//
#include <hip/hip_runtime.h>
#include <hip/hip_bf16.h>
#include <math.h>

// ---------------------------------------------------------------------------
// SAContrastiveAdversarialLoss on MI355X (gfx950)
// B=8192, D=128, S=64. Output: scalar fp32.
//
// R6: R1's proven spill-free barrier-free main structure, but operands in
// FP8 e4m3 (OCP). Rationale: R1 was latency-bound because Abuf+Kc = 6 MB
// bf16 thrashes the 4 MiB per-XCD L2 (B loads served by L3 at ~450-900cyc;
// 4 waves/SIMD can't hide it). fp8 shrinks the set to 3 MB -> L2-resident
// (~200cyc), and halves fragment registers (afrag 64->32, bfrag 16->8) so
// ~6 waves/SIMD fit. fp8 16x16x32 MFMA runs at bf16 rate, same instr count.
// Precision: per-row log error <= 0.04, /134M normalization -> ~2e-6 total,
// threshold is 19.12. Numerator & diagonal stay fp32.
// R2/R3/R5 lesson kept: NO register prefetch, NO LDS pipeline, NO barriers
// in the main loop - every such attempt spilled (96-275 MB scratch).
// ---------------------------------------------------------------------------

#define NROWS 8192
#define DFEAT 128

typedef float f32x4 __attribute__((ext_vector_type(4)));
typedef long long frag8;  // 8 fp8 elems = 2 VGPRs

__device__ __forceinline__ float fexp2(float x) {
#if __has_builtin(__builtin_amdgcn_exp2f)
  return __builtin_amdgcn_exp2f(x);
#else
  return exp2f(x);
#endif
}

__device__ __forceinline__ unsigned short pack_fp8(float x, float y) {
  return (unsigned short)(__builtin_amdgcn_cvt_pk_fp8_f32(x, y, 0, false) &
                          0xffff);
}

// ---------------------------------------------------------------------------
// prep: one wave per row. Computes row norms + diagonal dots, writes
//   Abuf[row] = fp8( n1 * 10*log2(e) )    (A operand, scale folded in)
//   Kc[row]         = fp8( n2 )           (keys for e12)
//   Kc[8192+row]    = fp8( n1 )           (keys for e11)
//   numv[row] = exp(10*cos(z1,z2)),  d11v[row] = exp(10*cos(z1,z1))  [fp32]
// Also zeroes T[row] and (block 0) the output scalar.
__global__ void sa_prep_kernel(const float* __restrict__ z1,
                               const float* __restrict__ z2,
                               unsigned char* __restrict__ Abuf,
                               unsigned char* __restrict__ Kc,
                               float* __restrict__ numv,
                               float* __restrict__ d11v,
                               float* __restrict__ T,
                               float* __restrict__ out) {
  int wave = threadIdx.x >> 6;
  int lane = threadIdx.x & 63;
  int row  = blockIdx.x * 4 + wave;

  const float2* z1p = (const float2*)(z1 + row * DFEAT);
  const float2* z2p = (const float2*)(z2 + row * DFEAT);
  float2 a = z1p[lane];
  float2 b = z2p[lane];

  float s1  = a.x * a.x + a.y * a.y;
  float s2  = b.x * b.x + b.y * b.y;
  float s12 = a.x * b.x + a.y * b.y;
#pragma unroll
  for (int m = 32; m; m >>= 1) {
    s1  += __shfl_xor(s1, m, 64);
    s2  += __shfl_xor(s2, m, 64);
    s12 += __shfl_xor(s12, m, 64);
  }
  float r1 = 1.0f / fmaxf(sqrtf(s1), 1e-8f);  // COS_EPS
  float r2 = 1.0f / fmaxf(sqrtf(s2), 1e-8f);

  const float SCL = 14.426950408889634f;  // 10 * log2(e), folds /tau + exp2

  // elem i lives at byte i; lane covers elems 2*lane, 2*lane+1.
  ((unsigned short*)(Abuf + row * DFEAT))[lane] =
      pack_fp8(a.x * r1 * SCL, a.y * r1 * SCL);
  ((unsigned short*)(Kc + row * DFEAT))[lane] = pack_fp8(b.x * r2, b.y * r2);
  ((unsigned short*)(Kc + (NROWS + row) * DFEAT))[lane] =
      pack_fp8(a.x * r1, a.y * r1);

  if (lane == 0) {
    numv[row] = expf(10.0f * s12 * r1 * r2);
    d11v[row] = expf(10.0f * s1 * r1 * r1);
    T[row]    = 0.0f;
  }
  if (blockIdx.x == 0 && threadIdx.x == 0) out[0] = 0.0f;
}

// ---------------------------------------------------------------------------
// main: fused "row-sum of exp(sim)" over the virtual 8192x16384 matrix.
// Each wave owns 64 query rows (A fragments in registers, 4 strips of 16)
// and a 256-column chunk of keys (16 tiles of 16 cols). Per tile: 4 B-frag
// dwordx2 loads (L2-resident fp8 Kc), 16 MFMAs, 16 exp2+add. Latency hidden
// by TLP (~6 waves/SIMD at this register footprint).
// fp8 16x16x32 layouts (dtype-independent, m121/m127): A: m=lane&15,
// k=quad*8+j (byte j of the i64); B: n=lane&15, same k. C/D: col=lane&15,
// row=quad*4+reg.
__global__ __launch_bounds__(256)
void sa_main_kernel(const unsigned char* __restrict__ Abuf,
                    const unsigned char* __restrict__ Kc,
                    float* __restrict__ T) {
  int wave = threadIdx.x >> 6;
  int lane = threadIdx.x & 63;
  int quad = lane >> 4;
  int l15  = lane & 15;

  int rowBase = blockIdx.x * 64;
  int chunk   = blockIdx.y * 4 + wave;   // 0..63
  int colBase = chunk * 256;

  // A fragments for 4 row-strips (reused across the whole column loop)
  frag8 afrag[4][4];
#pragma unroll
  for (int s = 0; s < 4; ++s) {
    const unsigned char* ap =
        Abuf + (rowBase + s * 16 + l15) * DFEAT + quad * 8;
#pragma unroll
    for (int kf = 0; kf < 4; ++kf)
      afrag[s][kf] = *(const frag8*)(ap + kf * 32);
  }

  f32x4 sums[4];
#pragma unroll
  for (int s = 0; s < 4; ++s) sums[s] = (f32x4){0.f, 0.f, 0.f, 0.f};

  for (int ct = 0; ct < 16; ++ct) {
    int col = colBase + ct * 16 + l15;
    const unsigned char* bp = Kc + col * DFEAT + quad * 8;
    frag8 bfrag[4];
#pragma unroll
    for (int kf = 0; kf < 4; ++kf)
      bfrag[kf] = *(const frag8*)(bp + kf * 32);

#pragma unroll
    for (int s = 0; s < 4; ++s) {
      f32x4 c = {0.f, 0.f, 0.f, 0.f};
#pragma unroll
      for (int kf = 0; kf < 4; ++kf)
        c = __builtin_amdgcn_mfma_f32_16x16x32_fp8_fp8(afrag[s][kf], bfrag[kf],
                                                       c, 0, 0, 0);
#pragma unroll
      for (int r = 0; r < 4; ++r)
        sums[s][r] += fexp2(c[r]);
    }
  }

  // Reduce across the 16 lanes of each quad-group (cols), then one lane
  // per quad commits 4 row partial-sums.
#pragma unroll
  for (int s = 0; s < 4; ++s) {
#pragma unroll
    for (int r = 0; r < 4; ++r) {
      float v = sums[s][r];
      v += __shfl_xor(v, 1, 64);
      v += __shfl_xor(v, 2, 64);
      v += __shfl_xor(v, 4, 64);
      v += __shfl_xor(v, 8, 64);
      if (l15 == 0)
        atomicAdd(&T[rowBase + s * 16 + quad * 4 + r], v);
    }
  }
}

// ---------------------------------------------------------------------------
// tail: adversarial term (one wave per row, S=64 == wave width) fused with
// the per-row contrastive finalize (lane 0 of each wave).
__global__ void sa_tail_kernel(const float* __restrict__ T,
                               const float* __restrict__ numv,
                               const float* __restrict__ d11v,
                               const float* __restrict__ c,
                               const float* __restrict__ lab,
                               float* __restrict__ out) {
  int wave = threadIdx.x >> 6;
  int lane = threadIdx.x & 63;
  int row  = blockIdx.x * 4 + wave;

  float cv = c[row * 64 + lane];
  float lv = lab[row * 64 + lane];

  float ss = cv * cv;
  float bestv = lv;
  int   besti = lane;
#pragma unroll
  for (int m = 32; m; m >>= 1) {
    ss += __shfl_xor(ss, m, 64);
    float ov = __shfl_xor(bestv, m, 64);
    int   oi = __shfl_xor(besti, m, 64);
    if (ov > bestv || (ov == bestv && oi < besti)) { bestv = ov; besti = oi; }
  }
  float picked = __shfl(cv, besti, 64) / fmaxf(sqrtf(ss), 1e-12f);
  float term = -logf(1e-12f + 1.0f - picked);  // LAM = 1

  __shared__ float acc[4];
  if (lane == 0) {
    float denom = T[row] - d11v[row];
    float v = -logf(1e-12f + numv[row] / denom);
    term += v * (1.0f / 134209536.0f);  // 1 / (B*(2B-1)) = 1/(8192*16383)
    acc[wave] = term;
  }
  __syncthreads();
  if (threadIdx.x == 0)
    atomicAdd(out, acc[0] + acc[1] + acc[2] + acc[3]);
}

// ---------------------------------------------------------------------------
extern "C" void kernel_launch(void* const* d_in, const int* in_sizes, int n_in,
                              void* d_out, int out_size, void* d_ws,
                              size_t ws_size, hipStream_t stream) {
  const float* z1  = (const float*)d_in[0];  // [8192,128]
  const float* z2  = (const float*)d_in[1];  // [8192,128]
  const float* co  = (const float*)d_in[2];  // [8192,64]
  const float* lab = (const float*)d_in[3];  // [8192,64]
  float* out = (float*)d_out;

  char* ws = (char*)d_ws;
  unsigned char* Abuf = (unsigned char*)ws;                  // 1 MB
  unsigned char* Kc   = (unsigned char*)(ws + 1u * 1024 * 1024);  // 2 MB
  float*  T    = (float*)(ws + 3u * 1024 * 1024);            // 32 KB
  float*  numv = T + NROWS;
  float*  d11v = numv + NROWS;

  sa_prep_kernel<<<NROWS / 4, 256, 0, stream>>>(z1, z2, Abuf, Kc, numv, d11v,
                                                T, out);
  sa_main_kernel<<<dim3(NROWS / 64, 16), 256, 0, stream>>>(Abuf, Kc, T);
  sa_tail_kernel<<<NROWS / 4, 256, 0, stream>>>(T, numv, d11v, co, lab, out);
}